// Round 2
// baseline (4830.473 us; speedup 1.0000x reference)
//
#include <hip/hip_runtime.h>
#include <hip/hip_bf16.h>
#include <cstdint>
#include <cstddef>

#define T_LEN 512
#define B_SZ  512
#define F_IN  64
#define H_DIM 128
#define NSTEP 8

__device__ __forceinline__ float fsig(float x) { return 1.0f / (1.0f + __expf(-x)); }
__device__ __forceinline__ float ftanh(float x) {
  float e = __expf(-2.0f * fabsf(x));
  float t = (1.0f - e) / (1.0f + e);
  return copysignf(t, x);
}

// Generic 4-element vector load -> float4 (fp32 or bf16 storage)
__device__ __forceinline__ float4 ldk4(const float* p) { return *(const float4*)p; }
__device__ __forceinline__ float4 ldk4(const __hip_bfloat16* p) {
  const ushort4 u = *(const ushort4*)p;
  float4 r;
  r.x = __uint_as_float(((unsigned)u.x) << 16);
  r.y = __uint_as_float(((unsigned)u.y) << 16);
  r.z = __uint_as_float(((unsigned)u.z) << 16);
  r.w = __uint_as_float(((unsigned)u.w) << 16);
  return r;
}
__device__ __forceinline__ void stk1(float* p, float v) { *p = v; }
__device__ __forceinline__ void stk1(__hip_bfloat16* p, float v) { *p = __float2bfloat16(v); }

// -------------------------------------------------------------------------
// Encoder GRU layer, fused input projection. One block per batch row.
// 768 threads: tid = ks*48 + jg; ks in [0,16) is a 16-wide K slice of the
// concatenated K = [h(128) | x(128, zero-padded for layer 0)], jg in [0,48)
// owns 8 output columns j = jg*8+jj. Weights live in registers (128 f/thread).
// xin/buf may alias (in-place across layers; each block touches only row b).
// -------------------------------------------------------------------------
__global__ __launch_bounds__(768) void enc_layer(
    const float* xin, float* buf,
    const float* __restrict__ w_ih, const float* __restrict__ w_hh,
    const float* __restrict__ b_ih, const float* __restrict__ b_hh,
    int d_in, int is_layer0)
{
  __shared__ float hx[256];          // [h(128) | x(128)]
  __shared__ float psum[16][388];    // padded to break bank alignment
  __shared__ float ahl[384], axl[384];
  __shared__ float bihl[384], bhhl[384];

  const int b    = blockIdx.x;
  const int tid  = threadIdx.x;
  const int ks   = tid / 48;
  const int jg   = tid - ks * 48;
  const int koff = ks * 16;

  // Load this thread's 8x16 weight patch into registers.
  float wreg[8][16];
  #pragma unroll
  for (int jj = 0; jj < 8; ++jj) {
    const int j = jg * 8 + jj;
    #pragma unroll
    for (int kk = 0; kk < 16; ++kk) {
      const int k = koff + kk;
      float w;
      if (k < H_DIM) {
        w = w_hh[j * H_DIM + k];
      } else {
        const int kx = k - H_DIM;
        w = (kx < d_in) ? w_ih[j * d_in + kx] : 0.0f;
      }
      wreg[jj][kk] = w;
    }
  }

  if (tid < 384) { bihl[tid] = b_ih[tid]; bhhl[tid] = b_hh[tid]; }
  if (tid < 128) {
    hx[tid] = 0.0f;                          // h0 = 0
  } else if (tid < 256) {
    const int c2 = tid - 128;                // stage x_0
    float v;
    if (is_layer0) v = (c2 < F_IN) ? xin[(size_t)b * (T_LEN * F_IN) + c2] : 0.0f;
    else           v = xin[(size_t)b * H_DIM + c2];
    hx[128 + c2] = v;
  }
  __syncthreads();

  for (int t = 0; t < T_LEN; ++t) {
    // ---- phase 1: fused GEMM (gh and gx partials) ----
    float acc[8];
    {
      const float4 a0 = *(const float4*)&hx[koff + 0];
      const float4 a1 = *(const float4*)&hx[koff + 4];
      const float4 a2 = *(const float4*)&hx[koff + 8];
      const float4 a3 = *(const float4*)&hx[koff + 12];
      #pragma unroll
      for (int jj = 0; jj < 8; ++jj) {
        float s;
        s  = a0.x * wreg[jj][0];  s += a0.y * wreg[jj][1];
        s += a0.z * wreg[jj][2];  s += a0.w * wreg[jj][3];
        s += a1.x * wreg[jj][4];  s += a1.y * wreg[jj][5];
        s += a1.z * wreg[jj][6];  s += a1.w * wreg[jj][7];
        s += a2.x * wreg[jj][8];  s += a2.y * wreg[jj][9];
        s += a2.z * wreg[jj][10]; s += a2.w * wreg[jj][11];
        s += a3.x * wreg[jj][12]; s += a3.y * wreg[jj][13];
        s += a3.z * wreg[jj][14]; s += a3.w * wreg[jj][15];
        acc[jj] = s;
      }
    }
    *(float4*)&psum[ks][jg * 8 + 0] = make_float4(acc[0], acc[1], acc[2], acc[3]);
    *(float4*)&psum[ks][jg * 8 + 4] = make_float4(acc[4], acc[5], acc[6], acc[7]);
    __syncthreads();

    // ---- phase 2: K-slice reduction (h-part / x-part kept separate) + x prefetch ----
    if (tid < 384) {
      float sh = 0.0f, sx = 0.0f;
      #pragma unroll
      for (int s = 0; s < 8; ++s)  sh += psum[s][tid];
      #pragma unroll
      for (int s = 8; s < 16; ++s) sx += psum[s][tid];
      ahl[tid] = sh; axl[tid] = sx;
    } else if (tid < 512) {
      const int c2 = tid - 384;
      const int tn = t + 1;
      if (tn < T_LEN) {
        float v;
        if (is_layer0) v = (c2 < F_IN) ? xin[((size_t)b * T_LEN + tn) * F_IN + c2] : 0.0f;
        else           v = xin[((size_t)tn * B_SZ + b) * H_DIM + c2];
        hx[128 + c2] = v;
      }
    }
    __syncthreads();

    // ---- phase 3: gates + state update + output write ----
    if (tid < 128) {
      const int c = tid;
      const float hold = hx[c];
      const float rp = axl[c]       + bihl[c]       + ahl[c]       + bhhl[c];
      const float zp = axl[128 + c] + bihl[128 + c] + ahl[128 + c] + bhhl[128 + c];
      const float nx = axl[256 + c] + bihl[256 + c];
      const float nh = ahl[256 + c] + bhhl[256 + c];
      const float r = fsig(rp);
      const float z = fsig(zp);
      const float n = ftanh(nx + r * nh);
      const float hnew = (1.0f - z) * n + z * hold;
      hx[c] = hnew;
      buf[((size_t)t * B_SZ + b) * H_DIM + c] = hnew;
    }
    __syncthreads();
  }
}

// -------------------------------------------------------------------------
// keys = enc @ aWk.T + abk.  A: (T*B,128) rows (T,B,H); out stored (B,T,H).
// 64-row x 128-col tile per block, per-thread 8x4 micro-tile, K chunked by 32.
// -------------------------------------------------------------------------
template <typename KT>
__global__ __launch_bounds__(256) void keys_gemm(
    const float* __restrict__ A, const float* __restrict__ W,
    const float* __restrict__ bias, KT* __restrict__ out)
{
  __shared__ float AT[32][64];    // [k][m]
  __shared__ float WT[32][128];   // [k][n]
  const int tid = threadIdx.x;
  const int m0  = blockIdx.x * 64;
  const int mi  = tid >> 5;
  const int ni  = tid & 31;
  const int mr  = mi * 8;
  const int n0  = ni * 4;

  float acc[8][4];
  #pragma unroll
  for (int i = 0; i < 8; ++i)
    #pragma unroll
    for (int q = 0; q < 4; ++q) acc[i][q] = 0.0f;

  for (int kc = 0; kc < 128; kc += 32) {
    __syncthreads();
    for (int i = tid; i < 512; i += 256) {          // stage A (transposed)
      const int m = i >> 3, k4 = (i & 7) * 4;
      const float4 v = *(const float4*)&A[((size_t)(m0 + m)) * 128 + kc + k4];
      AT[k4 + 0][m] = v.x; AT[k4 + 1][m] = v.y; AT[k4 + 2][m] = v.z; AT[k4 + 3][m] = v.w;
    }
    for (int i = tid; i < 1024; i += 256) {         // stage W (transposed)
      const int n = i >> 3, k4 = (i & 7) * 4;
      const float4 v = *(const float4*)&W[n * 128 + kc + k4];
      WT[k4 + 0][n] = v.x; WT[k4 + 1][n] = v.y; WT[k4 + 2][n] = v.z; WT[k4 + 3][n] = v.w;
    }
    __syncthreads();
    #pragma unroll 8
    for (int k = 0; k < 32; ++k) {
      const float4 wv = *(const float4*)&WT[k][n0];
      const float4 a0 = *(const float4*)&AT[k][mr];
      const float4 a1 = *(const float4*)&AT[k][mr + 4];
      acc[0][0] += a0.x * wv.x; acc[0][1] += a0.x * wv.y; acc[0][2] += a0.x * wv.z; acc[0][3] += a0.x * wv.w;
      acc[1][0] += a0.y * wv.x; acc[1][1] += a0.y * wv.y; acc[1][2] += a0.y * wv.z; acc[1][3] += a0.y * wv.w;
      acc[2][0] += a0.z * wv.x; acc[2][1] += a0.z * wv.y; acc[2][2] += a0.z * wv.z; acc[2][3] += a0.z * wv.w;
      acc[3][0] += a0.w * wv.x; acc[3][1] += a0.w * wv.y; acc[3][2] += a0.w * wv.z; acc[3][3] += a0.w * wv.w;
      acc[4][0] += a1.x * wv.x; acc[4][1] += a1.x * wv.y; acc[4][2] += a1.x * wv.z; acc[4][3] += a1.x * wv.w;
      acc[5][0] += a1.y * wv.x; acc[5][1] += a1.y * wv.y; acc[5][2] += a1.y * wv.z; acc[5][3] += a1.y * wv.w;
      acc[6][0] += a1.z * wv.x; acc[6][1] += a1.z * wv.y; acc[6][2] += a1.z * wv.z; acc[6][3] += a1.z * wv.w;
      acc[7][0] += a1.w * wv.x; acc[7][1] += a1.w * wv.y; acc[7][2] += a1.w * wv.z; acc[7][3] += a1.w * wv.w;
    }
  }
  const float4 bb = *(const float4*)&bias[n0];
  #pragma unroll
  for (int i = 0; i < 8; ++i) {
    const int m = m0 + mr + i;
    const int t = m >> 9;         // row index in (T,B)
    const int b = m & 511;
    KT* op = out + ((size_t)b * T_LEN + t) * 128 + n0;
    stk1(op + 0, acc[i][0] + bb.x);
    stk1(op + 1, acc[i][1] + bb.y);
    stk1(op + 2, acc[i][2] + bb.z);
    stk1(op + 3, acc[i][3] + bb.w);
  }
}

// -------------------------------------------------------------------------
// Decoder: one block per batch row, 8 attention+GRU+head steps in-kernel.
// enc layout (T,B,H); keys layout (B,T,H). h0 = enc[T-1, b].
// Small weights read untransposed (row-per-thread, float4 along k; L2-hot).
// -------------------------------------------------------------------------
template <typename KT>
__global__ __launch_bounds__(256) void decoder(
    const float* __restrict__ enc, const KT* __restrict__ keys,
    const float* __restrict__ aWq, const float* __restrict__ abq,
    const float* __restrict__ av,
    const float* __restrict__ dwih, const float* __restrict__ dwhh,
    const float* __restrict__ dbih, const float* __restrict__ dbhh,
    const float* __restrict__ lng, const float* __restrict__ lnb,
    const float* __restrict__ w1, const float* __restrict__ b1,
    const float* __restrict__ w2, const float* __restrict__ b2,
    float* __restrict__ out)
{
  __shared__ float h_s[128], q_s[128], s_s[512], w_s[512];
  __shared__ float part[2][128], u_s[256], gx_s[384], gh_s[384], y_s[128];
  __shared__ float red[8];
  const int b = blockIdx.x, tid = threadIdx.x;

  if (tid < 128) h_s[tid] = enc[((size_t)(T_LEN - 1) * B_SZ + b) * 128 + tid];
  __syncthreads();

  for (int step = 0; step < NSTEP; ++step) {
    // q = h @ aWq.T + abq   (thread tid owns output row tid)
    if (tid < 128) {
      float acc = abq[tid];
      const float* wr = &aWq[(size_t)tid * 128];
      #pragma unroll 8
      for (int k4 = 0; k4 < 32; ++k4) {
        const float4 hv = *(const float4*)&h_s[k4 * 4];
        const float4 wv = *(const float4*)&wr[k4 * 4];
        acc += hv.x * wv.x + hv.y * wv.y + hv.z * wv.z + hv.w * wv.w;
      }
      q_s[tid] = acc;
    }
    __syncthreads();
    // scores over T (keys contiguous per block: (B,T,H))
    for (int tt = tid; tt < 512; tt += 256) {
      const KT* kp = keys + ((size_t)b * T_LEN + tt) * 128;
      float acc = 0.0f;
      #pragma unroll 4
      for (int c4 = 0; c4 < 32; ++c4) {
        const float4 kv = ldk4(kp + c4 * 4);
        const float4 qv = *(const float4*)&q_s[c4 * 4];
        const float4 a4 = *(const float4*)&av[c4 * 4];
        acc += ftanh(kv.x + qv.x) * a4.x + ftanh(kv.y + qv.y) * a4.y
             + ftanh(kv.z + qv.z) * a4.z + ftanh(kv.w + qv.w) * a4.w;
      }
      s_s[tt] = acc;
    }
    __syncthreads();
    // softmax over T
    {
      float m0 = fmaxf(s_s[tid], s_s[tid + 256]);
      #pragma unroll
      for (int o = 32; o; o >>= 1) m0 = fmaxf(m0, __shfl_xor(m0, o, 64));
      if ((tid & 63) == 0) red[tid >> 6] = m0;
      __syncthreads();
      const float mx = fmaxf(fmaxf(red[0], red[1]), fmaxf(red[2], red[3]));
      const float e0 = __expf(s_s[tid] - mx);
      const float e1 = __expf(s_s[tid + 256] - mx);
      float sm = e0 + e1;
      #pragma unroll
      for (int o = 32; o; o >>= 1) sm += __shfl_xor(sm, o, 64);
      if ((tid & 63) == 0) red[4 + (tid >> 6)] = sm;
      __syncthreads();
      const float inv = 1.0f / (red[4] + red[5] + red[6] + red[7]);
      w_s[tid] = e0 * inv;
      w_s[tid + 256] = e1 * inv;
    }
    __syncthreads();
    // ctx = sum_t w[t] * enc[t, b, :]
    {
      const int c = tid & 127, th = tid >> 7;
      const float* ep = enc + (size_t)(th * 256) * B_SZ * 128 + (size_t)b * 128 + c;
      float acc = 0.0f;
      #pragma unroll 4
      for (int q = 0; q < 256; ++q)
        acc += w_s[th * 256 + q] * ep[(size_t)q * B_SZ * 128];
      part[th][c] = acc;
    }
    __syncthreads();
    if (tid < 128) { u_s[tid] = part[0][tid] + part[1][tid]; u_s[128 + tid] = h_s[tid]; }
    __syncthreads();
    // decoder GRU gates (thread owns output row j; rows read untransposed)
    for (int j = tid; j < 384; j += 256) {
      float gx = dbih[j], gh = dbhh[j];
      const float* wxr = &dwih[(size_t)j * 256];
      const float* whr = &dwhh[(size_t)j * 128];
      #pragma unroll 8
      for (int k4 = 0; k4 < 64; ++k4) {
        const float4 uv = *(const float4*)&u_s[k4 * 4];
        const float4 wv = *(const float4*)&wxr[k4 * 4];
        gx += uv.x * wv.x + uv.y * wv.y + uv.z * wv.z + uv.w * wv.w;
      }
      #pragma unroll 8
      for (int k4 = 0; k4 < 32; ++k4) {
        const float4 hv = *(const float4*)&h_s[k4 * 4];
        const float4 wv = *(const float4*)&whr[k4 * 4];
        gh += hv.x * wv.x + hv.y * wv.y + hv.z * wv.z + hv.w * wv.w;
      }
      gx_s[j] = gx; gh_s[j] = gh;
    }
    __syncthreads();
    // combine + LN stats
    if (tid < 128) {
      const float r = fsig(gx_s[tid] + gh_s[tid]);
      const float z = fsig(gx_s[128 + tid] + gh_s[128 + tid]);
      const float n = ftanh(gx_s[256 + tid] + r * gh_s[256 + tid]);
      const float hn = (1.0f - z) * n + z * h_s[tid];
      h_s[tid] = hn;
      float s1 = hn, s2 = hn * hn;
      #pragma unroll
      for (int o = 32; o; o >>= 1) { s1 += __shfl_xor(s1, o, 64); s2 += __shfl_xor(s2, o, 64); }
      if ((tid & 63) == 0) { red[tid >> 6] = s1; red[4 + (tid >> 6)] = s2; }
    }
    __syncthreads();
    if (tid < 128) {
      const float hn  = h_s[tid];
      const float mu  = (red[0] + red[1]) * (1.0f / 128.0f);
      const float var = (red[4] + red[5]) * (1.0f / 128.0f) - mu * mu;
      y_s[tid] = (hn - mu) / sqrtf(var + 1e-5f) * lng[tid] + lnb[tid];
    }
    __syncthreads();
    // head: relu(y @ w1.T + b1) @ w2.T + b2
    if (tid < 64) {
      float acc = b1[tid];
      const float* wr = &w1[(size_t)tid * 128];
      #pragma unroll 8
      for (int k4 = 0; k4 < 32; ++k4) {
        const float4 yv = *(const float4*)&y_s[k4 * 4];
        const float4 wv = *(const float4*)&wr[k4 * 4];
        acc += yv.x * wv.x + yv.y * wv.y + yv.z * wv.z + yv.w * wv.w;
      }
      acc = fmaxf(acc, 0.0f);
      float v = acc * w2[tid];
      #pragma unroll
      for (int o = 32; o; o >>= 1) v += __shfl_xor(v, o, 64);
      if (tid == 0) out[(size_t)b * NSTEP + step] = v + b2[0];
    }
    __syncthreads();
  }
}

// -------------------------------------------------------------------------
extern "C" void kernel_launch(void* const* d_in, const int* in_sizes, int n_in,
                              void* d_out, int out_size, void* d_ws, size_t ws_size,
                              hipStream_t stream)
{
  (void)in_sizes; (void)n_in; (void)out_size;
  const float* x    = (const float*)d_in[0];
  const float* ewih[3] = {(const float*)d_in[1], (const float*)d_in[5], (const float*)d_in[9]};
  const float* ewhh[3] = {(const float*)d_in[2], (const float*)d_in[6], (const float*)d_in[10]};
  const float* ebih[3] = {(const float*)d_in[3], (const float*)d_in[7], (const float*)d_in[11]};
  const float* ebhh[3] = {(const float*)d_in[4], (const float*)d_in[8], (const float*)d_in[12]};
  const float* aWq  = (const float*)d_in[13];
  const float* abq  = (const float*)d_in[14];
  const float* aWk  = (const float*)d_in[15];
  const float* abk  = (const float*)d_in[16];
  const float* av   = (const float*)d_in[17];
  const float* dwih = (const float*)d_in[18];
  const float* dwhh = (const float*)d_in[19];
  const float* dbih = (const float*)d_in[20];
  const float* dbhh = (const float*)d_in[21];
  const float* lng  = (const float*)d_in[22];
  const float* lnb  = (const float*)d_in[23];
  const float* w1   = (const float*)d_in[24];
  const float* b1   = (const float*)d_in[25];
  const float* w2   = (const float*)d_in[26];
  const float* b2   = (const float*)d_in[27];

  const size_t ENC_ELEMS = (size_t)T_LEN * B_SZ * H_DIM;   // 33,554,432
  float* buf = (float*)d_ws;                                // (T,B,H) fp32, 128 MiB

  enc_layer<<<dim3(512), dim3(768), 0, stream>>>(x,   buf, ewih[0], ewhh[0], ebih[0], ebhh[0], 64, 1);
  enc_layer<<<dim3(512), dim3(768), 0, stream>>>(buf, buf, ewih[1], ewhh[1], ebih[1], ebhh[1], 128, 0);
  enc_layer<<<dim3(512), dim3(768), 0, stream>>>(buf, buf, ewih[2], ewhh[2], ebih[2], ebhh[2], 128, 0);

  const size_t need_f32 = ENC_ELEMS * 4 * 2;                // 256 MiB
  if (ws_size >= need_f32) {
    float* keys = (float*)d_ws + ENC_ELEMS;                 // (B,T,H) fp32
    keys_gemm<float><<<dim3(4096), dim3(256), 0, stream>>>(buf, aWk, abk, keys);
    decoder<float><<<dim3(512), dim3(256), 0, stream>>>(
        buf, keys, aWq, abq, av, dwih, dwhh, dbih, dbhh,
        lng, lnb, w1, b1, w2, b2, (float*)d_out);
  } else {
    __hip_bfloat16* keys = (__hip_bfloat16*)((float*)d_ws + ENC_ELEMS);  // (B,T,H) bf16
    keys_gemm<__hip_bfloat16><<<dim3(4096), dim3(256), 0, stream>>>(buf, aWk, abk, keys);
    decoder<__hip_bfloat16><<<dim3(512), dim3(256), 0, stream>>>(
        buf, keys, aWq, abq, av, dwih, dwhh, dbih, dbhh,
        lng, lnb, w1, b1, w2, b2, (float*)d_out);
  }
}

// Round 3
// 4072.260 us; speedup vs baseline: 1.1862x; 1.1862x over previous
//
#include <hip/hip_runtime.h>
#include <hip/hip_bf16.h>
#include <cstdint>
#include <cstddef>

#define T_LEN 512
#define B_SZ  512
#define F_IN  64
#define H_DIM 128
#define NSTEP 8
#define T_CHUNK 128

typedef __attribute__((ext_vector_type(8))) short short8;
typedef __attribute__((ext_vector_type(4))) float f32x4;

__device__ __forceinline__ float fsig(float x) { return 1.0f / (1.0f + __expf(-x)); }
__device__ __forceinline__ float ftanh(float x) {
  float e = __expf(-2.0f * fabsf(x));
  float t = (1.0f - e) / (1.0f + e);
  return copysignf(t, x);
}
__device__ __forceinline__ unsigned short bf16hi(float x) {
  __hip_bfloat16 h = __float2bfloat16(x);
  return *(unsigned short*)&h;
}
__device__ __forceinline__ float bf2f(unsigned short u) {
  return __uint_as_float(((unsigned)u) << 16);
}

// Generic 4-element vector load -> float4 (fp32 or bf16 storage)
__device__ __forceinline__ float4 ldk4(const float* p) { return *(const float4*)p; }
__device__ __forceinline__ float4 ldk4(const __hip_bfloat16* p) {
  const ushort4 u = *(const ushort4*)p;
  float4 r;
  r.x = bf2f(u.x); r.y = bf2f(u.y); r.z = bf2f(u.z); r.w = bf2f(u.w);
  return r;
}
__device__ __forceinline__ void stk1(float* p, float v) { *p = v; }
__device__ __forceinline__ void stk1(__hip_bfloat16* p, float v) { *p = __float2bfloat16(v); }

// -------------------------------------------------------------------------
// Split the 3 encoder w_ih matrices into bf16 hi/lo pairs (one-time prep).
// Concatenated layout: [0,24576)=l0(384x64), [24576,73728)=l1, [73728,122880)=l2
// -------------------------------------------------------------------------
__global__ __launch_bounds__(256) void prep_split(
    const float* __restrict__ w0, const float* __restrict__ w1,
    const float* __restrict__ w2,
    unsigned short* __restrict__ hi, unsigned short* __restrict__ lo)
{
  const int i = blockIdx.x * 256 + threadIdx.x;
  if (i >= 122880) return;
  float v = (i < 24576) ? w0[i] : ((i < 73728) ? w1[i - 24576] : w2[i - 73728]);
  const unsigned short h = bf16hi(v);
  hi[i] = h;
  lo[i] = bf16hi(v - bf2f(h));
}

// -------------------------------------------------------------------------
// gx = A @ W^T + b_ih for one T-chunk, split-bf16 MFMA (3 products).
// A: layer0 x (B,T,64) else buf (T,B,128). Row m (chunk-local) -> (t0+m>>9, m&511).
// Block: 256 thr / 4 waves; tile BM=64 (wave w: rows w*16..), BN=128 (8 n-tiles).
// gx out: (T_CHUNK, B, 384), includes b_ih.
// -------------------------------------------------------------------------
__global__ __launch_bounds__(256) void gx_gemm(
    const float* __restrict__ A,
    const unsigned short* __restrict__ Whi, const unsigned short* __restrict__ Wlo,
    const float* __restrict__ b_ih, float* __restrict__ gx,
    int t0, int k_dim, int is_layer0)
{
  __shared__ unsigned short Ah[64 * 40], Al[64 * 40];
  __shared__ unsigned short Bh[128 * 40], Bl[128 * 40];
  const int tid  = threadIdx.x;
  const int wave = tid >> 6, lane = tid & 63;
  const int quad = lane >> 4, l16 = lane & 15;
  const int m0 = blockIdx.x * 64;
  const int n0 = blockIdx.y * 128;

  f32x4 acc[8];
  #pragma unroll
  for (int i = 0; i < 8; ++i) acc[i] = (f32x4){0.f, 0.f, 0.f, 0.f};

  float bias[8];
  #pragma unroll
  for (int nt = 0; nt < 8; ++nt) bias[nt] = b_ih[n0 + nt * 16 + l16];

  for (int kc = 0; kc < k_dim; kc += 32) {
    __syncthreads();
    // stage A tile 64x32 fp32 -> hi/lo bf16 (512 float4s, 2/thread)
    #pragma unroll
    for (int g = tid; g < 512; g += 256) {
      const int r = g >> 3, c4 = (g & 7) * 4;
      const int m = m0 + r;
      const int tg = t0 + (m >> 9), b = m & 511;
      const float* ap = is_layer0 ? &A[((size_t)b * T_LEN + tg) * 64]
                                  : &A[((size_t)tg * B_SZ + b) * 128];
      const float4 v = *(const float4*)&ap[kc + c4];
      const unsigned short h0 = bf16hi(v.x), h1 = bf16hi(v.y),
                           h2 = bf16hi(v.z), h3 = bf16hi(v.w);
      ushort4 hv; hv.x = h0; hv.y = h1; hv.z = h2; hv.w = h3;
      ushort4 lv;
      lv.x = bf16hi(v.x - bf2f(h0)); lv.y = bf16hi(v.y - bf2f(h1));
      lv.z = bf16hi(v.z - bf2f(h2)); lv.w = bf16hi(v.w - bf2f(h3));
      *(ushort4*)&Ah[r * 40 + c4] = hv;
      *(ushort4*)&Al[r * 40 + c4] = lv;
    }
    // stage B tile 128x32 bf16 hi/lo (512 x 8-ushort groups, 2/thread)
    #pragma unroll
    for (int g = tid; g < 512; g += 256) {
      const int r = g >> 2, c8 = (g & 3) * 8;
      const size_t src = (size_t)(n0 + r) * k_dim + kc + c8;
      *(uint4*)&Bh[r * 40 + c8] = *(const uint4*)&Whi[src];
      *(uint4*)&Bl[r * 40 + c8] = *(const uint4*)&Wlo[src];
    }
    __syncthreads();

    const short8 a_hi = *(const short8*)&Ah[(wave * 16 + l16) * 40 + quad * 8];
    const short8 a_lo = *(const short8*)&Al[(wave * 16 + l16) * 40 + quad * 8];
    #pragma unroll
    for (int nt = 0; nt < 8; ++nt) {
      const short8 b_hi = *(const short8*)&Bh[(nt * 16 + l16) * 40 + quad * 8];
      const short8 b_lo = *(const short8*)&Bl[(nt * 16 + l16) * 40 + quad * 8];
      acc[nt] = __builtin_amdgcn_mfma_f32_16x16x32_bf16(a_hi, b_hi, acc[nt], 0, 0, 0);
      acc[nt] = __builtin_amdgcn_mfma_f32_16x16x32_bf16(a_hi, b_lo, acc[nt], 0, 0, 0);
      acc[nt] = __builtin_amdgcn_mfma_f32_16x16x32_bf16(a_lo, b_hi, acc[nt], 0, 0, 0);
    }
  }
  // C/D: col = lane&15, row = quad*4 + reg  [m89-verified]
  #pragma unroll
  for (int nt = 0; nt < 8; ++nt) {
    #pragma unroll
    for (int reg = 0; reg < 4; ++reg) {
      const int m = m0 + wave * 16 + quad * 4 + reg;
      const int n = n0 + nt * 16 + l16;
      gx[(size_t)m * 384 + n] = acc[nt][reg] + bias[nt];
    }
  }
}

// -------------------------------------------------------------------------
// Recurrence-only GRU chunk: gh = h @ w_hh^T + b_hh, gates, h update.
// 256 blocks (2 batch rows each), 768 threads: thread = (j=tid>>1, half=tid&1),
// holds w_hh[j, half*64..+63] in 16 float4 regs. Pair-reduce via shfl_xor(1).
// gx chunk (incl b_ih) prefetched 1 step ahead into double-buffered LDS.
// -------------------------------------------------------------------------
__global__ __launch_bounds__(768, 3) void rec_layer(
    const float* __restrict__ gx,   // (T_CHUNK, B, 384)
    const float* __restrict__ w_hh, const float* __restrict__ b_hh,
    float* __restrict__ buf,        // (T, B, 128)
    float* __restrict__ h_state,    // (B, 128)
    int t0, int chunk0)
{
  __shared__ float hs[2][128];
  __shared__ float ghs[2][384];
  __shared__ float gxs[2][2][384];
  __shared__ float bhl[384];

  const int tid  = threadIdx.x;
  const int j    = tid >> 1, half = tid & 1;
  const int b0   = blockIdx.x * 2;
  const int gr   = (tid >= 384) ? 1 : 0;
  const int gidx = tid - (gr ? 384 : 0);

  float4 w4[16];
  {
    const float* wp = &w_hh[(size_t)j * 128 + half * 64];
    #pragma unroll
    for (int i = 0; i < 16; ++i) w4[i] = *(const float4*)&wp[i * 4];
  }
  if (tid < 384) bhl[tid] = b_hh[tid];
  if (tid < 256) {
    const int r = tid >> 7, c = tid & 127;
    hs[r][c] = chunk0 ? 0.0f : h_state[(size_t)(b0 + r) * 128 + c];
  }
  gxs[0][gr][gidx] = gx[(size_t)(b0 + gr) * 384 + gidx];   // t_local = 0
  __syncthreads();

  for (int tl = 0; tl < T_CHUNK; ++tl) {
    // prefetch next step's gx (global, hidden under FMA phase)
    float gxn = 0.0f;
    if (tl + 1 < T_CHUNK)
      gxn = gx[((size_t)(tl + 1) * B_SZ + b0 + gr) * 384 + gidx];
    // gh partial dot (K-half per thread), both batch rows share weights
    float acc0 = 0.0f, acc1 = 0.0f;
    #pragma unroll
    for (int i = 0; i < 16; ++i) {
      const float4 h0 = *(const float4*)&hs[0][half * 64 + i * 4];
      const float4 h1 = *(const float4*)&hs[1][half * 64 + i * 4];
      acc0 += h0.x * w4[i].x + h0.y * w4[i].y + h0.z * w4[i].z + h0.w * w4[i].w;
      acc1 += h1.x * w4[i].x + h1.y * w4[i].y + h1.z * w4[i].z + h1.w * w4[i].w;
    }
    acc0 += __shfl_xor(acc0, 1, 64);
    acc1 += __shfl_xor(acc1, 1, 64);
    if (half == 0) { ghs[0][j] = acc0 + bhl[j]; ghs[1][j] = acc1 + bhl[j]; }
    gxs[(tl + 1) & 1][gr][gidx] = gxn;
    __syncthreads();

    if (tid < 256) {
      const int rr = tid >> 7, c = tid & 127;
      const float* gxp = gxs[tl & 1][rr];
      const float rg = fsig(gxp[c] + ghs[rr][c]);
      const float zg = fsig(gxp[128 + c] + ghs[rr][128 + c]);
      const float ng = ftanh(gxp[256 + c] + rg * ghs[rr][256 + c]);
      const float hn = (1.0f - zg) * ng + zg * hs[rr][c];
      hs[rr][c] = hn;
      buf[((size_t)(t0 + tl) * B_SZ + b0 + rr) * 128 + c] = hn;
    }
    __syncthreads();
  }
  if (tid < 256) {
    const int r = tid >> 7, c = tid & 127;
    h_state[(size_t)(b0 + r) * 128 + c] = hs[r][c];
  }
}

// -------------------------------------------------------------------------
// keys = enc @ aWk.T + abk.  A: (T*B,128) rows (T,B,H); out stored (B,T,H).
// -------------------------------------------------------------------------
template <typename KT>
__global__ __launch_bounds__(256) void keys_gemm(
    const float* __restrict__ A, const float* __restrict__ W,
    const float* __restrict__ bias, KT* __restrict__ out)
{
  __shared__ float AT[32][64];
  __shared__ float WT[32][128];
  const int tid = threadIdx.x;
  const int m0  = blockIdx.x * 64;
  const int mi  = tid >> 5;
  const int ni  = tid & 31;
  const int mr  = mi * 8;
  const int n0  = ni * 4;

  float acc[8][4];
  #pragma unroll
  for (int i = 0; i < 8; ++i)
    #pragma unroll
    for (int q = 0; q < 4; ++q) acc[i][q] = 0.0f;

  for (int kc = 0; kc < 128; kc += 32) {
    __syncthreads();
    for (int i = tid; i < 512; i += 256) {
      const int m = i >> 3, k4 = (i & 7) * 4;
      const float4 v = *(const float4*)&A[((size_t)(m0 + m)) * 128 + kc + k4];
      AT[k4 + 0][m] = v.x; AT[k4 + 1][m] = v.y; AT[k4 + 2][m] = v.z; AT[k4 + 3][m] = v.w;
    }
    for (int i = tid; i < 1024; i += 256) {
      const int n = i >> 3, k4 = (i & 7) * 4;
      const float4 v = *(const float4*)&W[n * 128 + kc + k4];
      WT[k4 + 0][n] = v.x; WT[k4 + 1][n] = v.y; WT[k4 + 2][n] = v.z; WT[k4 + 3][n] = v.w;
    }
    __syncthreads();
    #pragma unroll 8
    for (int k = 0; k < 32; ++k) {
      const float4 wv = *(const float4*)&WT[k][n0];
      const float4 a0 = *(const float4*)&AT[k][mr];
      const float4 a1 = *(const float4*)&AT[k][mr + 4];
      acc[0][0] += a0.x * wv.x; acc[0][1] += a0.x * wv.y; acc[0][2] += a0.x * wv.z; acc[0][3] += a0.x * wv.w;
      acc[1][0] += a0.y * wv.x; acc[1][1] += a0.y * wv.y; acc[1][2] += a0.y * wv.z; acc[1][3] += a0.y * wv.w;
      acc[2][0] += a0.z * wv.x; acc[2][1] += a0.z * wv.y; acc[2][2] += a0.z * wv.z; acc[2][3] += a0.z * wv.w;
      acc[3][0] += a0.w * wv.x; acc[3][1] += a0.w * wv.y; acc[3][2] += a0.w * wv.z; acc[3][3] += a0.w * wv.w;
      acc[4][0] += a1.x * wv.x; acc[4][1] += a1.x * wv.y; acc[4][2] += a1.x * wv.z; acc[4][3] += a1.x * wv.w;
      acc[5][0] += a1.y * wv.x; acc[5][1] += a1.y * wv.y; acc[5][2] += a1.y * wv.z; acc[5][3] += a1.y * wv.w;
      acc[6][0] += a1.z * wv.x; acc[6][1] += a1.z * wv.y; acc[6][2] += a1.z * wv.z; acc[6][3] += a1.z * wv.w;
      acc[7][0] += a1.w * wv.x; acc[7][1] += a1.w * wv.y; acc[7][2] += a1.w * wv.z; acc[7][3] += a1.w * wv.w;
    }
  }
  const float4 bb = *(const float4*)&bias[n0];
  #pragma unroll
  for (int i = 0; i < 8; ++i) {
    const int m = m0 + mr + i;
    const int t = m >> 9;
    const int b = m & 511;
    KT* op = out + ((size_t)b * T_LEN + t) * 128 + n0;
    stk1(op + 0, acc[i][0] + bb.x);
    stk1(op + 1, acc[i][1] + bb.y);
    stk1(op + 2, acc[i][2] + bb.z);
    stk1(op + 3, acc[i][3] + bb.w);
  }
}

// -------------------------------------------------------------------------
// Decoder: one block per batch row, 8 attention+GRU+head steps in-kernel.
// -------------------------------------------------------------------------
template <typename KT>
__global__ __launch_bounds__(256) void decoder(
    const float* __restrict__ enc, const KT* __restrict__ keys,
    const float* __restrict__ aWq, const float* __restrict__ abq,
    const float* __restrict__ av,
    const float* __restrict__ dwih, const float* __restrict__ dwhh,
    const float* __restrict__ dbih, const float* __restrict__ dbhh,
    const float* __restrict__ lng, const float* __restrict__ lnb,
    const float* __restrict__ w1, const float* __restrict__ b1,
    const float* __restrict__ w2, const float* __restrict__ b2,
    float* __restrict__ out)
{
  __shared__ float h_s[128], q_s[128], s_s[512], w_s[512];
  __shared__ float part[2][128], u_s[256], gx_s[384], gh_s[384], y_s[128];
  __shared__ float red[8];
  const int b = blockIdx.x, tid = threadIdx.x;

  if (tid < 128) h_s[tid] = enc[((size_t)(T_LEN - 1) * B_SZ + b) * 128 + tid];
  __syncthreads();

  for (int step = 0; step < NSTEP; ++step) {
    if (tid < 128) {
      float acc = abq[tid];
      const float* wr = &aWq[(size_t)tid * 128];
      #pragma unroll 8
      for (int k4 = 0; k4 < 32; ++k4) {
        const float4 hv = *(const float4*)&h_s[k4 * 4];
        const float4 wv = *(const float4*)&wr[k4 * 4];
        acc += hv.x * wv.x + hv.y * wv.y + hv.z * wv.z + hv.w * wv.w;
      }
      q_s[tid] = acc;
    }
    __syncthreads();
    for (int tt = tid; tt < 512; tt += 256) {
      const KT* kp = keys + ((size_t)b * T_LEN + tt) * 128;
      float acc = 0.0f;
      #pragma unroll 4
      for (int c4 = 0; c4 < 32; ++c4) {
        const float4 kv = ldk4(kp + c4 * 4);
        const float4 qv = *(const float4*)&q_s[c4 * 4];
        const float4 a4 = *(const float4*)&av[c4 * 4];
        acc += ftanh(kv.x + qv.x) * a4.x + ftanh(kv.y + qv.y) * a4.y
             + ftanh(kv.z + qv.z) * a4.z + ftanh(kv.w + qv.w) * a4.w;
      }
      s_s[tt] = acc;
    }
    __syncthreads();
    {
      float m0 = fmaxf(s_s[tid], s_s[tid + 256]);
      #pragma unroll
      for (int o = 32; o; o >>= 1) m0 = fmaxf(m0, __shfl_xor(m0, o, 64));
      if ((tid & 63) == 0) red[tid >> 6] = m0;
      __syncthreads();
      const float mx = fmaxf(fmaxf(red[0], red[1]), fmaxf(red[2], red[3]));
      const float e0 = __expf(s_s[tid] - mx);
      const float e1 = __expf(s_s[tid + 256] - mx);
      float sm = e0 + e1;
      #pragma unroll
      for (int o = 32; o; o >>= 1) sm += __shfl_xor(sm, o, 64);
      if ((tid & 63) == 0) red[4 + (tid >> 6)] = sm;
      __syncthreads();
      const float inv = 1.0f / (red[4] + red[5] + red[6] + red[7]);
      w_s[tid] = e0 * inv;
      w_s[tid + 256] = e1 * inv;
    }
    __syncthreads();
    {
      const int c = tid & 127, th = tid >> 7;
      const float* ep = enc + (size_t)(th * 256) * B_SZ * 128 + (size_t)b * 128 + c;
      float acc = 0.0f;
      #pragma unroll 4
      for (int q = 0; q < 256; ++q)
        acc += w_s[th * 256 + q] * ep[(size_t)q * B_SZ * 128];
      part[th][c] = acc;
    }
    __syncthreads();
    if (tid < 128) { u_s[tid] = part[0][tid] + part[1][tid]; u_s[128 + tid] = h_s[tid]; }
    __syncthreads();
    for (int jj = tid; jj < 384; jj += 256) {
      float gxv = dbih[jj], ghv = dbhh[jj];
      const float* wxr = &dwih[(size_t)jj * 256];
      const float* whr = &dwhh[(size_t)jj * 128];
      #pragma unroll 8
      for (int k4 = 0; k4 < 64; ++k4) {
        const float4 uv = *(const float4*)&u_s[k4 * 4];
        const float4 wv = *(const float4*)&wxr[k4 * 4];
        gxv += uv.x * wv.x + uv.y * wv.y + uv.z * wv.z + uv.w * wv.w;
      }
      #pragma unroll 8
      for (int k4 = 0; k4 < 32; ++k4) {
        const float4 hv = *(const float4*)&h_s[k4 * 4];
        const float4 wv = *(const float4*)&whr[k4 * 4];
        ghv += hv.x * wv.x + hv.y * wv.y + hv.z * wv.z + hv.w * wv.w;
      }
      gx_s[jj] = gxv; gh_s[jj] = ghv;
    }
    __syncthreads();
    if (tid < 128) {
      const float r = fsig(gx_s[tid] + gh_s[tid]);
      const float z = fsig(gx_s[128 + tid] + gh_s[128 + tid]);
      const float n = ftanh(gx_s[256 + tid] + r * gh_s[256 + tid]);
      const float hn = (1.0f - z) * n + z * h_s[tid];
      h_s[tid] = hn;
      float s1 = hn, s2 = hn * hn;
      #pragma unroll
      for (int o = 32; o; o >>= 1) { s1 += __shfl_xor(s1, o, 64); s2 += __shfl_xor(s2, o, 64); }
      if ((tid & 63) == 0) { red[tid >> 6] = s1; red[4 + (tid >> 6)] = s2; }
    }
    __syncthreads();
    if (tid < 128) {
      const float hn  = h_s[tid];
      const float mu  = (red[0] + red[1]) * (1.0f / 128.0f);
      const float var = (red[4] + red[5]) * (1.0f / 128.0f) - mu * mu;
      y_s[tid] = (hn - mu) / sqrtf(var + 1e-5f) * lng[tid] + lnb[tid];
    }
    __syncthreads();
    if (tid < 64) {
      float acc = b1[tid];
      const float* wr = &w1[(size_t)tid * 128];
      #pragma unroll 8
      for (int k4 = 0; k4 < 32; ++k4) {
        const float4 yv = *(const float4*)&y_s[k4 * 4];
        const float4 wv = *(const float4*)&wr[k4 * 4];
        acc += yv.x * wv.x + yv.y * wv.y + yv.z * wv.z + yv.w * wv.w;
      }
      acc = fmaxf(acc, 0.0f);
      float v = acc * w2[tid];
      #pragma unroll
      for (int o = 32; o; o >>= 1) v += __shfl_xor(v, o, 64);
      if (tid == 0) out[(size_t)b * NSTEP + step] = v + b2[0];
    }
    __syncthreads();
  }
}

// -------------------------------------------------------------------------
extern "C" void kernel_launch(void* const* d_in, const int* in_sizes, int n_in,
                              void* d_out, int out_size, void* d_ws, size_t ws_size,
                              hipStream_t stream)
{
  (void)in_sizes; (void)n_in; (void)out_size;
  const float* x    = (const float*)d_in[0];
  const float* ewih[3] = {(const float*)d_in[1], (const float*)d_in[5], (const float*)d_in[9]};
  const float* ewhh[3] = {(const float*)d_in[2], (const float*)d_in[6], (const float*)d_in[10]};
  const float* ebih[3] = {(const float*)d_in[3], (const float*)d_in[7], (const float*)d_in[11]};
  const float* ebhh[3] = {(const float*)d_in[4], (const float*)d_in[8], (const float*)d_in[12]};
  const float* aWq  = (const float*)d_in[13];
  const float* abq  = (const float*)d_in[14];
  const float* aWk  = (const float*)d_in[15];
  const float* abk  = (const float*)d_in[16];
  const float* av   = (const float*)d_in[17];
  const float* dwih = (const float*)d_in[18];
  const float* dwhh = (const float*)d_in[19];
  const float* dbih = (const float*)d_in[20];
  const float* dbhh = (const float*)d_in[21];
  const float* lng  = (const float*)d_in[22];
  const float* lnb  = (const float*)d_in[23];
  const float* w1   = (const float*)d_in[24];
  const float* b1   = (const float*)d_in[25];
  const float* w2   = (const float*)d_in[26];
  const float* b2   = (const float*)d_in[27];

  const size_t ENC_ELEMS = (size_t)T_LEN * B_SZ * H_DIM;       // 33,554,432 f
  const size_t GX_ELEMS  = (size_t)T_CHUNK * B_SZ * 384;       // 25,165,824 f
  float* ws      = (float*)d_ws;
  float* buf     = ws;                                          // [0, 33.5M)
  float* gxc     = ws + ENC_ELEMS;                              // [33.5M, 58.7M)
  float* h_state = ws + ENC_ELEMS + GX_ELEMS;                   // 65,536 f
  unsigned short* Whi = (unsigned short*)(h_state + 65536);     // 122,880 ush
  unsigned short* Wlo = Whi + 122880;                           // ends < 67.1M f

  prep_split<<<dim3(480), dim3(256), 0, stream>>>(ewih[0], ewih[1], ewih[2], Whi, Wlo);

  const int koff[3] = {0, 24576, 73728};
  const int kdim[3] = {64, 128, 128};
  for (int l = 0; l < 3; ++l) {
    for (int c = 0; c < 4; ++c) {
      const int t0 = c * T_CHUNK;
      gx_gemm<<<dim3(1024, 3), dim3(256), 0, stream>>>(
          (l == 0) ? x : buf, Whi + koff[l], Wlo + koff[l], ebih[l],
          gxc, t0, kdim[l], (l == 0) ? 1 : 0);
      rec_layer<<<dim3(256), dim3(768), 0, stream>>>(
          gxc, ewhh[l], ebhh[l], buf, h_state, t0, (c == 0) ? 1 : 0);
    }
  }

  // keys + decoder: keys region reuses gx-chunk memory (gx dead now).
  const size_t need_f32 = ENC_ELEMS * 4 * 2;                    // 256 MiB
  if (ws_size >= need_f32) {
    float* keys = ws + ENC_ELEMS;                               // (B,T,H) fp32
    keys_gemm<float><<<dim3(4096), dim3(256), 0, stream>>>(buf, aWk, abk, keys);
    decoder<float><<<dim3(512), dim3(256), 0, stream>>>(
        buf, keys, aWq, abq, av, dwih, dwhh, dbih, dbhh,
        lng, lnb, w1, b1, w2, b2, (float*)d_out);
  } else {
    __hip_bfloat16* keys = (__hip_bfloat16*)(ws + ENC_ELEMS);   // (B,T,H) bf16
    keys_gemm<__hip_bfloat16><<<dim3(4096), dim3(256), 0, stream>>>(buf, aWk, abk, keys);
    decoder<__hip_bfloat16><<<dim3(512), dim3(256), 0, stream>>>(
        buf, keys, aWq, abq, av, dwih, dwhh, dbih, dbhh,
        lng, lnb, w1, b1, w2, b2, (float*)d_out);
  }
}

// Round 4
// 3389.609 us; speedup vs baseline: 1.4251x; 1.2014x over previous
//
#include <hip/hip_runtime.h>
#include <hip/hip_bf16.h>
#include <cstdint>
#include <cstddef>

#define T_LEN 512
#define B_SZ  512
#define F_IN  64
#define H_DIM 128
#define NSTEP 8
#define T_CHUNK 128

typedef __attribute__((ext_vector_type(8))) short short8;
typedef __attribute__((ext_vector_type(4))) float f32x4;

__device__ __forceinline__ float fsig(float x) { return 1.0f / (1.0f + __expf(-x)); }
__device__ __forceinline__ float ftanh(float x) {
  float e = __expf(-2.0f * fabsf(x));
  float t = (1.0f - e) / (1.0f + e);
  return copysignf(t, x);
}
__device__ __forceinline__ unsigned short bf16hi(float x) {
  __hip_bfloat16 h = __float2bfloat16(x);
  return *(unsigned short*)&h;
}
__device__ __forceinline__ float bf2f(unsigned short u) {
  return __uint_as_float(((unsigned)u) << 16);
}

// DPP cross-lane add: v += lane-permuted(v). CTRL compile-time constant.
// 0xB1 = quad_perm[1,0,3,2] (xor1), 0x4E = quad_perm[2,3,0,1] (xor2),
// 0x124 = row_ror:4, 0x128 = row_ror:8 (within 16-lane row).
template <int CTRL>
__device__ __forceinline__ float dpp_add(float v) {
  int p = __builtin_amdgcn_update_dpp(0, __float_as_int(v), CTRL, 0xF, 0xF, true);
  return v + __int_as_float(p);
}
__device__ __forceinline__ float row_sum16(float v) {
  v = dpp_add<0xB1>(v);
  v = dpp_add<0x4E>(v);
  v = dpp_add<0x124>(v);
  v = dpp_add<0x128>(v);
  return v;
}

// Generic 4-element vector load -> float4 (fp32 or bf16 storage)
__device__ __forceinline__ float4 ldk4(const float* p) { return *(const float4*)p; }
__device__ __forceinline__ float4 ldk4(const __hip_bfloat16* p) {
  const ushort4 u = *(const ushort4*)p;
  float4 r;
  r.x = bf2f(u.x); r.y = bf2f(u.y); r.z = bf2f(u.z); r.w = bf2f(u.w);
  return r;
}
__device__ __forceinline__ void stk1(float* p, float v) { *p = v; }
__device__ __forceinline__ void stk1(__hip_bfloat16* p, float v) { *p = __float2bfloat16(v); }

// padded h index: 8 data + 4 pad floats per group (16B-aligned float4s,
// bank aliasing <= 2-way which is free)
__device__ __forceinline__ int hidx(int k) { return (k >> 3) * 12 + (k & 7); }

// -------------------------------------------------------------------------
// Split the 3 encoder w_ih matrices into bf16 hi/lo pairs (one-time prep).
// -------------------------------------------------------------------------
__global__ __launch_bounds__(256) void prep_split(
    const float* __restrict__ w0, const float* __restrict__ w1,
    const float* __restrict__ w2,
    unsigned short* __restrict__ hi, unsigned short* __restrict__ lo)
{
  const int i = blockIdx.x * 256 + threadIdx.x;
  if (i >= 122880) return;
  float v = (i < 24576) ? w0[i] : ((i < 73728) ? w1[i - 24576] : w2[i - 73728]);
  const unsigned short h = bf16hi(v);
  hi[i] = h;
  lo[i] = bf16hi(v - bf2f(h));
}

// -------------------------------------------------------------------------
// gx = A @ W^T + b_ih for one T-chunk, split-bf16 MFMA (3 products).
// -------------------------------------------------------------------------
__global__ __launch_bounds__(256) void gx_gemm(
    const float* __restrict__ A,
    const unsigned short* __restrict__ Whi, const unsigned short* __restrict__ Wlo,
    const float* __restrict__ b_ih, float* __restrict__ gx,
    int t0, int k_dim, int is_layer0)
{
  __shared__ unsigned short Ah[64 * 40], Al[64 * 40];
  __shared__ unsigned short Bh[128 * 40], Bl[128 * 40];
  const int tid  = threadIdx.x;
  const int wave = tid >> 6, lane = tid & 63;
  const int quad = lane >> 4, l16 = lane & 15;
  const int m0 = blockIdx.x * 64;
  const int n0 = blockIdx.y * 128;

  f32x4 acc[8];
  #pragma unroll
  for (int i = 0; i < 8; ++i) acc[i] = (f32x4){0.f, 0.f, 0.f, 0.f};

  float bias[8];
  #pragma unroll
  for (int nt = 0; nt < 8; ++nt) bias[nt] = b_ih[n0 + nt * 16 + l16];

  for (int kc = 0; kc < k_dim; kc += 32) {
    __syncthreads();
    #pragma unroll
    for (int g = tid; g < 512; g += 256) {
      const int r = g >> 3, c4 = (g & 7) * 4;
      const int m = m0 + r;
      const int tg = t0 + (m >> 9), b = m & 511;
      const float* ap = is_layer0 ? &A[((size_t)b * T_LEN + tg) * 64]
                                  : &A[((size_t)tg * B_SZ + b) * 128];
      const float4 v = *(const float4*)&ap[kc + c4];
      const unsigned short h0 = bf16hi(v.x), h1 = bf16hi(v.y),
                           h2 = bf16hi(v.z), h3 = bf16hi(v.w);
      ushort4 hv; hv.x = h0; hv.y = h1; hv.z = h2; hv.w = h3;
      ushort4 lv;
      lv.x = bf16hi(v.x - bf2f(h0)); lv.y = bf16hi(v.y - bf2f(h1));
      lv.z = bf16hi(v.z - bf2f(h2)); lv.w = bf16hi(v.w - bf2f(h3));
      *(ushort4*)&Ah[r * 40 + c4] = hv;
      *(ushort4*)&Al[r * 40 + c4] = lv;
    }
    #pragma unroll
    for (int g = tid; g < 512; g += 256) {
      const int r = g >> 2, c8 = (g & 3) * 8;
      const size_t src = (size_t)(n0 + r) * k_dim + kc + c8;
      *(uint4*)&Bh[r * 40 + c8] = *(const uint4*)&Whi[src];
      *(uint4*)&Bl[r * 40 + c8] = *(const uint4*)&Wlo[src];
    }
    __syncthreads();

    const short8 a_hi = *(const short8*)&Ah[(wave * 16 + l16) * 40 + quad * 8];
    const short8 a_lo = *(const short8*)&Al[(wave * 16 + l16) * 40 + quad * 8];
    #pragma unroll
    for (int nt = 0; nt < 8; ++nt) {
      const short8 b_hi = *(const short8*)&Bh[(nt * 16 + l16) * 40 + quad * 8];
      const short8 b_lo = *(const short8*)&Bl[(nt * 16 + l16) * 40 + quad * 8];
      acc[nt] = __builtin_amdgcn_mfma_f32_16x16x32_bf16(a_hi, b_hi, acc[nt], 0, 0, 0);
      acc[nt] = __builtin_amdgcn_mfma_f32_16x16x32_bf16(a_hi, b_lo, acc[nt], 0, 0, 0);
      acc[nt] = __builtin_amdgcn_mfma_f32_16x16x32_bf16(a_lo, b_hi, acc[nt], 0, 0, 0);
    }
  }
  #pragma unroll
  for (int nt = 0; nt < 8; ++nt) {
    #pragma unroll
    for (int reg = 0; reg < 4; ++reg) {
      const int m = m0 + wave * 16 + quad * 4 + reg;
      const int n = n0 + nt * 16 + l16;
      gx[(size_t)m * 384 + n] = acc[nt][reg] + bias[nt];
    }
  }
}

// -------------------------------------------------------------------------
// Recurrence-only GRU chunk. 256 blocks x 2 batch rows, 768 threads.
// lane = jg*16 + ks (jg in [0,4), ks in [0,16)). Thread owns 8 j's
// (J0 = (wave*4+jg)*8) and 8 k's (ks*8..+8): 64 weight floats in VGPRs.
// k-reduction fully in-register via DPP (xor1,xor2,ror4,ror8). One lane
// per 16 writes gh. LDS insts/CU/step: ~48 reads + 48 masked writes
// (was ~384 broadcast b128 reads in R3).
// -------------------------------------------------------------------------
__global__ __launch_bounds__(768, 3) void rec_layer(
    const float* __restrict__ gx,   // (T_CHUNK, B, 384), includes b_ih
    const float* __restrict__ w_hh, const float* __restrict__ b_hh,
    float* __restrict__ buf,        // (T, B, 128)
    float* __restrict__ h_state,    // (B, 128)
    int t0, int chunk0)
{
  __shared__ float hs[2][196];      // padded: hidx(k) = (k>>3)*12 + (k&7)
  __shared__ float ghs[2][384];
  __shared__ float gxs[2][2][384];
  __shared__ float bhl[384];

  const int tid  = threadIdx.x;
  const int wave = tid >> 6, lane = tid & 63;
  const int jg   = lane >> 4, ks = lane & 15;
  const int J0   = (wave * 4 + jg) * 8;
  const int b0   = blockIdx.x * 2;
  const int gr   = (tid >= 384) ? 1 : 0;
  const int gidx = tid - (gr ? 384 : 0);

  // weights: w_hh[J0+jj][ks*8 .. +8] -> 16 float4s (64 VGPRs)
  float4 w[8][2];
  #pragma unroll
  for (int jj = 0; jj < 8; ++jj) {
    const float* wp = &w_hh[(size_t)(J0 + jj) * 128 + ks * 8];
    w[jj][0] = *(const float4*)&wp[0];
    w[jj][1] = *(const float4*)&wp[4];
  }
  if (tid < 384) bhl[tid] = b_hh[tid];
  if (tid < 256) {
    const int r = tid >> 7, c = tid & 127;
    hs[r][hidx(c)] = chunk0 ? 0.0f : h_state[(size_t)(b0 + r) * 128 + c];
  }
  gxs[0][gr][gidx] = gx[(size_t)(b0 + gr) * 384 + gidx];   // t_local = 0
  __syncthreads();

  for (int tl = 0; tl < T_CHUNK; ++tl) {
    // prefetch next step's gx (coalesced; hidden under FMA phase)
    float gxn = 0.0f;
    if (tl + 1 < T_CHUNK)
      gxn = gx[((size_t)(tl + 1) * B_SZ + b0 + gr) * 384 + gidx];

    // partial dots: 4 b128 broadcast reads of h, 128 FMAs
    const float4 h00 = *(const float4*)&hs[0][ks * 12];
    const float4 h01 = *(const float4*)&hs[0][ks * 12 + 4];
    const float4 h10 = *(const float4*)&hs[1][ks * 12];
    const float4 h11 = *(const float4*)&hs[1][ks * 12 + 4];
    float a0[8], a1[8];
    #pragma unroll
    for (int jj = 0; jj < 8; ++jj) {
      a0[jj] = h00.x * w[jj][0].x + h00.y * w[jj][0].y
             + h00.z * w[jj][0].z + h00.w * w[jj][0].w
             + h01.x * w[jj][1].x + h01.y * w[jj][1].y
             + h01.z * w[jj][1].z + h01.w * w[jj][1].w;
      a1[jj] = h10.x * w[jj][0].x + h10.y * w[jj][0].y
             + h10.z * w[jj][0].z + h10.w * w[jj][0].w
             + h11.x * w[jj][1].x + h11.y * w[jj][1].y
             + h11.z * w[jj][1].z + h11.w * w[jj][1].w;
    }
    // in-register reduction over the 16 ks slices (per 16-lane row)
    #pragma unroll
    for (int jj = 0; jj < 8; ++jj) {
      a0[jj] = row_sum16(a0[jj]);
      a1[jj] = row_sum16(a1[jj]);
    }
    if (ks == 0) {
      *(float4*)&ghs[0][J0]     = make_float4(a0[0], a0[1], a0[2], a0[3]);
      *(float4*)&ghs[0][J0 + 4] = make_float4(a0[4], a0[5], a0[6], a0[7]);
      *(float4*)&ghs[1][J0]     = make_float4(a1[0], a1[1], a1[2], a1[3]);
      *(float4*)&ghs[1][J0 + 4] = make_float4(a1[4], a1[5], a1[6], a1[7]);
    }
    gxs[(tl + 1) & 1][gr][gidx] = gxn;
    __syncthreads();

    if (tid < 256) {
      const int rr = tid >> 7, c = tid & 127;
      const float* gxp = gxs[tl & 1][rr];
      const float rg = fsig(gxp[c]       + ghs[rr][c]       + bhl[c]);
      const float zg = fsig(gxp[128 + c] + ghs[rr][128 + c] + bhl[128 + c]);
      const float ng = ftanh(gxp[256 + c] + rg * (ghs[rr][256 + c] + bhl[256 + c]));
      const float hn = (1.0f - zg) * ng + zg * hs[rr][hidx(c)];
      hs[rr][hidx(c)] = hn;
      buf[((size_t)(t0 + tl) * B_SZ + b0 + rr) * 128 + c] = hn;
    }
    __syncthreads();
  }
  if (tid < 256) {
    const int r = tid >> 7, c = tid & 127;
    h_state[(size_t)(b0 + r) * 128 + c] = hs[r][hidx(c)];
  }
}

// -------------------------------------------------------------------------
// keys = enc @ aWk.T + abk.  A: (T*B,128) rows (T,B,H); out stored (B,T,H).
// -------------------------------------------------------------------------
template <typename KT>
__global__ __launch_bounds__(256) void keys_gemm(
    const float* __restrict__ A, const float* __restrict__ W,
    const float* __restrict__ bias, KT* __restrict__ out)
{
  __shared__ float AT[32][64];
  __shared__ float WT[32][128];
  const int tid = threadIdx.x;
  const int m0  = blockIdx.x * 64;
  const int mi  = tid >> 5;
  const int ni  = tid & 31;
  const int mr  = mi * 8;
  const int n0  = ni * 4;

  float acc[8][4];
  #pragma unroll
  for (int i = 0; i < 8; ++i)
    #pragma unroll
    for (int q = 0; q < 4; ++q) acc[i][q] = 0.0f;

  for (int kc = 0; kc < 128; kc += 32) {
    __syncthreads();
    for (int i = tid; i < 512; i += 256) {
      const int m = i >> 3, k4 = (i & 7) * 4;
      const float4 v = *(const float4*)&A[((size_t)(m0 + m)) * 128 + kc + k4];
      AT[k4 + 0][m] = v.x; AT[k4 + 1][m] = v.y; AT[k4 + 2][m] = v.z; AT[k4 + 3][m] = v.w;
    }
    for (int i = tid; i < 1024; i += 256) {
      const int n = i >> 3, k4 = (i & 7) * 4;
      const float4 v = *(const float4*)&W[n * 128 + kc + k4];
      WT[k4 + 0][n] = v.x; WT[k4 + 1][n] = v.y; WT[k4 + 2][n] = v.z; WT[k4 + 3][n] = v.w;
    }
    __syncthreads();
    #pragma unroll 8
    for (int k = 0; k < 32; ++k) {
      const float4 wv = *(const float4*)&WT[k][n0];
      const float4 a0 = *(const float4*)&AT[k][mr];
      const float4 a1 = *(const float4*)&AT[k][mr + 4];
      acc[0][0] += a0.x * wv.x; acc[0][1] += a0.x * wv.y; acc[0][2] += a0.x * wv.z; acc[0][3] += a0.x * wv.w;
      acc[1][0] += a0.y * wv.x; acc[1][1] += a0.y * wv.y; acc[1][2] += a0.y * wv.z; acc[1][3] += a0.y * wv.w;
      acc[2][0] += a0.z * wv.x; acc[2][1] += a0.z * wv.y; acc[2][2] += a0.z * wv.z; acc[2][3] += a0.z * wv.w;
      acc[3][0] += a0.w * wv.x; acc[3][1] += a0.w * wv.y; acc[3][2] += a0.w * wv.z; acc[3][3] += a0.w * wv.w;
      acc[4][0] += a1.x * wv.x; acc[4][1] += a1.x * wv.y; acc[4][2] += a1.x * wv.z; acc[4][3] += a1.x * wv.w;
      acc[5][0] += a1.y * wv.x; acc[5][1] += a1.y * wv.y; acc[5][2] += a1.y * wv.z; acc[5][3] += a1.y * wv.w;
      acc[6][0] += a1.z * wv.x; acc[6][1] += a1.z * wv.y; acc[6][2] += a1.z * wv.z; acc[6][3] += a1.z * wv.w;
      acc[7][0] += a1.w * wv.x; acc[7][1] += a1.w * wv.y; acc[7][2] += a1.w * wv.z; acc[7][3] += a1.w * wv.w;
    }
  }
  const float4 bb = *(const float4*)&bias[n0];
  #pragma unroll
  for (int i = 0; i < 8; ++i) {
    const int m = m0 + mr + i;
    const int t = m >> 9;
    const int b = m & 511;
    KT* op = out + ((size_t)b * T_LEN + t) * 128 + n0;
    stk1(op + 0, acc[i][0] + bb.x);
    stk1(op + 1, acc[i][1] + bb.y);
    stk1(op + 2, acc[i][2] + bb.z);
    stk1(op + 3, acc[i][3] + bb.w);
  }
}

// -------------------------------------------------------------------------
// Decoder: one block per batch row, 8 attention+GRU+head steps in-kernel.
// -------------------------------------------------------------------------
template <typename KT>
__global__ __launch_bounds__(256) void decoder(
    const float* __restrict__ enc, const KT* __restrict__ keys,
    const float* __restrict__ aWq, const float* __restrict__ abq,
    const float* __restrict__ av,
    const float* __restrict__ dwih, const float* __restrict__ dwhh,
    const float* __restrict__ dbih, const float* __restrict__ dbhh,
    const float* __restrict__ lng, const float* __restrict__ lnb,
    const float* __restrict__ w1, const float* __restrict__ b1,
    const float* __restrict__ w2, const float* __restrict__ b2,
    float* __restrict__ out)
{
  __shared__ float h_s[128], q_s[128], s_s[512], w_s[512];
  __shared__ float part[2][128], u_s[256], gx_s[384], gh_s[384], y_s[128];
  __shared__ float red[8];
  const int b = blockIdx.x, tid = threadIdx.x;

  if (tid < 128) h_s[tid] = enc[((size_t)(T_LEN - 1) * B_SZ + b) * 128 + tid];
  __syncthreads();

  for (int step = 0; step < NSTEP; ++step) {
    if (tid < 128) {
      float acc = abq[tid];
      const float* wr = &aWq[(size_t)tid * 128];
      #pragma unroll 8
      for (int k4 = 0; k4 < 32; ++k4) {
        const float4 hv = *(const float4*)&h_s[k4 * 4];
        const float4 wv = *(const float4*)&wr[k4 * 4];
        acc += hv.x * wv.x + hv.y * wv.y + hv.z * wv.z + hv.w * wv.w;
      }
      q_s[tid] = acc;
    }
    __syncthreads();
    for (int tt = tid; tt < 512; tt += 256) {
      const KT* kp = keys + ((size_t)b * T_LEN + tt) * 128;
      float acc = 0.0f;
      #pragma unroll 4
      for (int c4 = 0; c4 < 32; ++c4) {
        const float4 kv = ldk4(kp + c4 * 4);
        const float4 qv = *(const float4*)&q_s[c4 * 4];
        const float4 a4 = *(const float4*)&av[c4 * 4];
        acc += ftanh(kv.x + qv.x) * a4.x + ftanh(kv.y + qv.y) * a4.y
             + ftanh(kv.z + qv.z) * a4.z + ftanh(kv.w + qv.w) * a4.w;
      }
      s_s[tt] = acc;
    }
    __syncthreads();
    {
      float m0 = fmaxf(s_s[tid], s_s[tid + 256]);
      #pragma unroll
      for (int o = 32; o; o >>= 1) m0 = fmaxf(m0, __shfl_xor(m0, o, 64));
      if ((tid & 63) == 0) red[tid >> 6] = m0;
      __syncthreads();
      const float mx = fmaxf(fmaxf(red[0], red[1]), fmaxf(red[2], red[3]));
      const float e0 = __expf(s_s[tid] - mx);
      const float e1 = __expf(s_s[tid + 256] - mx);
      float sm = e0 + e1;
      #pragma unroll
      for (int o = 32; o; o >>= 1) sm += __shfl_xor(sm, o, 64);
      if ((tid & 63) == 0) red[4 + (tid >> 6)] = sm;
      __syncthreads();
      const float inv = 1.0f / (red[4] + red[5] + red[6] + red[7]);
      w_s[tid] = e0 * inv;
      w_s[tid + 256] = e1 * inv;
    }
    __syncthreads();
    {
      const int c = tid & 127, th = tid >> 7;
      const float* ep = enc + (size_t)(th * 256) * B_SZ * 128 + (size_t)b * 128 + c;
      float acc = 0.0f;
      #pragma unroll 4
      for (int q = 0; q < 256; ++q)
        acc += w_s[th * 256 + q] * ep[(size_t)q * B_SZ * 128];
      part[th][c] = acc;
    }
    __syncthreads();
    if (tid < 128) { u_s[tid] = part[0][tid] + part[1][tid]; u_s[128 + tid] = h_s[tid]; }
    __syncthreads();
    for (int jj = tid; jj < 384; jj += 256) {
      float gxv = dbih[jj], ghv = dbhh[jj];
      const float* wxr = &dwih[(size_t)jj * 256];
      const float* whr = &dwhh[(size_t)jj * 128];
      #pragma unroll 8
      for (int k4 = 0; k4 < 64; ++k4) {
        const float4 uv = *(const float4*)&u_s[k4 * 4];
        const float4 wv = *(const float4*)&wxr[k4 * 4];
        gxv += uv.x * wv.x + uv.y * wv.y + uv.z * wv.z + uv.w * wv.w;
      }
      #pragma unroll 8
      for (int k4 = 0; k4 < 32; ++k4) {
        const float4 hv = *(const float4*)&h_s[k4 * 4];
        const float4 wv = *(const float4*)&whr[k4 * 4];
        ghv += hv.x * wv.x + hv.y * wv.y + hv.z * wv.z + hv.w * wv.w;
      }
      gx_s[jj] = gxv; gh_s[jj] = ghv;
    }
    __syncthreads();
    if (tid < 128) {
      const float r = fsig(gx_s[tid] + gh_s[tid]);
      const float z = fsig(gx_s[128 + tid] + gh_s[128 + tid]);
      const float n = ftanh(gx_s[256 + tid] + r * gh_s[256 + tid]);
      const float hn = (1.0f - z) * n + z * h_s[tid];
      h_s[tid] = hn;
      float s1 = hn, s2 = hn * hn;
      #pragma unroll
      for (int o = 32; o; o >>= 1) { s1 += __shfl_xor(s1, o, 64); s2 += __shfl_xor(s2, o, 64); }
      if ((tid & 63) == 0) { red[tid >> 6] = s1; red[4 + (tid >> 6)] = s2; }
    }
    __syncthreads();
    if (tid < 128) {
      const float hn  = h_s[tid];
      const float mu  = (red[0] + red[1]) * (1.0f / 128.0f);
      const float var = (red[4] + red[5]) * (1.0f / 128.0f) - mu * mu;
      y_s[tid] = (hn - mu) / sqrtf(var + 1e-5f) * lng[tid] + lnb[tid];
    }
    __syncthreads();
    if (tid < 64) {
      float acc = b1[tid];
      const float* wr = &w1[(size_t)tid * 128];
      #pragma unroll 8
      for (int k4 = 0; k4 < 32; ++k4) {
        const float4 yv = *(const float4*)&y_s[k4 * 4];
        const float4 wv = *(const float4*)&wr[k4 * 4];
        acc += yv.x * wv.x + yv.y * wv.y + yv.z * wv.z + yv.w * wv.w;
      }
      acc = fmaxf(acc, 0.0f);
      float v = acc * w2[tid];
      #pragma unroll
      for (int o = 32; o; o >>= 1) v += __shfl_xor(v, o, 64);
      if (tid == 0) out[(size_t)b * NSTEP + step] = v + b2[0];
    }
    __syncthreads();
  }
}

// -------------------------------------------------------------------------
extern "C" void kernel_launch(void* const* d_in, const int* in_sizes, int n_in,
                              void* d_out, int out_size, void* d_ws, size_t ws_size,
                              hipStream_t stream)
{
  (void)in_sizes; (void)n_in; (void)out_size;
  const float* x    = (const float*)d_in[0];
  const float* ewih[3] = {(const float*)d_in[1], (const float*)d_in[5], (const float*)d_in[9]};
  const float* ewhh[3] = {(const float*)d_in[2], (const float*)d_in[6], (const float*)d_in[10]};
  const float* ebih[3] = {(const float*)d_in[3], (const float*)d_in[7], (const float*)d_in[11]};
  const float* ebhh[3] = {(const float*)d_in[4], (const float*)d_in[8], (const float*)d_in[12]};
  const float* aWq  = (const float*)d_in[13];
  const float* abq  = (const float*)d_in[14];
  const float* aWk  = (const float*)d_in[15];
  const float* abk  = (const float*)d_in[16];
  const float* av   = (const float*)d_in[17];
  const float* dwih = (const float*)d_in[18];
  const float* dwhh = (const float*)d_in[19];
  const float* dbih = (const float*)d_in[20];
  const float* dbhh = (const float*)d_in[21];
  const float* lng  = (const float*)d_in[22];
  const float* lnb  = (const float*)d_in[23];
  const float* w1   = (const float*)d_in[24];
  const float* b1   = (const float*)d_in[25];
  const float* w2   = (const float*)d_in[26];
  const float* b2   = (const float*)d_in[27];

  const size_t ENC_ELEMS = (size_t)T_LEN * B_SZ * H_DIM;       // 33,554,432 f
  const size_t GX_ELEMS  = (size_t)T_CHUNK * B_SZ * 384;       // 25,165,824 f
  float* ws      = (float*)d_ws;
  float* buf     = ws;
  float* gxc     = ws + ENC_ELEMS;
  float* h_state = ws + ENC_ELEMS + GX_ELEMS;
  unsigned short* Whi = (unsigned short*)(h_state + 65536);
  unsigned short* Wlo = Whi + 122880;

  prep_split<<<dim3(480), dim3(256), 0, stream>>>(ewih[0], ewih[1], ewih[2], Whi, Wlo);

  const int koff[3] = {0, 24576, 73728};
  const int kdim[3] = {64, 128, 128};
  for (int l = 0; l < 3; ++l) {
    for (int c = 0; c < 4; ++c) {
      const int t0 = c * T_CHUNK;
      gx_gemm<<<dim3(1024, 3), dim3(256), 0, stream>>>(
          (l == 0) ? x : buf, Whi + koff[l], Wlo + koff[l], ebih[l],
          gxc, t0, kdim[l], (l == 0) ? 1 : 0);
      rec_layer<<<dim3(256), dim3(768), 0, stream>>>(
          gxc, ewhh[l], ebhh[l], buf, h_state, t0, (c == 0) ? 1 : 0);
    }
  }

  const size_t need_f32 = ENC_ELEMS * 4 * 2;                    // 256 MiB
  if (ws_size >= need_f32) {
    float* keys = ws + ENC_ELEMS;
    keys_gemm<float><<<dim3(4096), dim3(256), 0, stream>>>(buf, aWk, abk, keys);
    decoder<float><<<dim3(512), dim3(256), 0, stream>>>(
        buf, keys, aWq, abq, av, dwih, dwhh, dbih, dbhh,
        lng, lnb, w1, b1, w2, b2, (float*)d_out);
  } else {
    __hip_bfloat16* keys = (__hip_bfloat16*)(ws + ENC_ELEMS);
    keys_gemm<__hip_bfloat16><<<dim3(4096), dim3(256), 0, stream>>>(buf, aWk, abk, keys);
    decoder<__hip_bfloat16><<<dim3(512), dim3(256), 0, stream>>>(
        buf, keys, aWq, abq, av, dwih, dwhh, dbih, dbhh,
        lng, lnb, w1, b1, w2, b2, (float*)d_out);
  }
}